// Round 13
// baseline (331.524 us; speedup 1.0000x reference)
//
#include <hip/hip_runtime.h>

#define D 128

typedef short bfrag __attribute__((ext_vector_type(8)));      // 8 bf16 = 4 VGPRs
typedef float f32x4 __attribute__((ext_vector_type(4)));
typedef unsigned uint32;

// ---------------- bf16 split helpers ----------------
__device__ inline unsigned short bf16_rne(float x) {
    unsigned u = __float_as_uint(x);
    return (unsigned short)((u + 0x7FFFu + ((u >> 16) & 1u)) >> 16);
}
__device__ inline float bf16_to_f(unsigned short h) {
    return __uint_as_float(((unsigned)h) << 16);
}
// pair word: hi in bits [15:0], lo in bits [31:16]
__device__ inline unsigned split2p(float x) {
    unsigned short hi = bf16_rne(x);
    unsigned short lo = bf16_rne(x - bf16_to_f(hi));
    return (unsigned)hi | ((unsigned)lo << 16);
}

// unpack 8 pair-words (2x uint4 regs) -> ah (8 hi bf16), al (8 lo bf16)
__device__ inline void unpair_r(uint4 q0, uint4 q1, bfrag& ah, bfrag& al) {
    union { uint32 u[4]; bfrag b; } H, L;
    H.u[0] = __builtin_amdgcn_perm(q0.y, q0.x, 0x05040100u);
    H.u[1] = __builtin_amdgcn_perm(q0.w, q0.z, 0x05040100u);
    H.u[2] = __builtin_amdgcn_perm(q1.y, q1.x, 0x05040100u);
    H.u[3] = __builtin_amdgcn_perm(q1.w, q1.z, 0x05040100u);
    L.u[0] = __builtin_amdgcn_perm(q0.y, q0.x, 0x07060302u);
    L.u[1] = __builtin_amdgcn_perm(q0.w, q0.z, 0x07060302u);
    L.u[2] = __builtin_amdgcn_perm(q1.y, q1.x, 0x07060302u);
    L.u[3] = __builtin_amdgcn_perm(q1.w, q1.z, 0x07060302u);
    ah = H.b;
    al = L.b;
}

// split 8 fp32 (2x uint4 regs, bit-cast) -> hi/lo bf16 fragments
__device__ inline void split8_r(uint4 q0, uint4 q1, bfrag& ah, bfrag& al) {
    float v[8] = {__uint_as_float(q0.x), __uint_as_float(q0.y), __uint_as_float(q0.z), __uint_as_float(q0.w),
                  __uint_as_float(q1.x), __uint_as_float(q1.y), __uint_as_float(q1.z), __uint_as_float(q1.w)};
    union { unsigned short us[8]; bfrag b; } H, L;
    #pragma unroll
    for (int i = 0; i < 8; i++) {
        unsigned pr = split2p(v[i]);
        H.us[i] = (unsigned short)pr;
        L.us[i] = (unsigned short)(pr >> 16);
    }
    ah = H.b;
    al = L.b;
}

// ---------------- degree from RAW edges (per-block dtype sampling) ----------------
__global__ __launch_bounds__(256) void deg_raw(const unsigned* __restrict__ raw, int* __restrict__ deg,
                                               int* __restrict__ gmode, int E) {
    __shared__ int smode;
    int p0 = blockIdx.x * 1024;
    if (threadIdx.x < 64) {
        int p = p0 + threadIdx.x * 16;
        unsigned v = (p < E) ? raw[2 * p + 1] : 0u;
        unsigned long long any = __ballot(v != 0u);
        if (threadIdx.x == 0) smode = (any != 0ull) ? 1 : 0;
    }
    __syncthreads();
    int m = smode;
    if (blockIdx.x == 0 && threadIdx.x == 0) *gmode = m;   // all blocks agree
    int pend = min(p0 + 1024, E);
    for (int p = p0 + threadIdx.x; p < pend; p += 256) {
        int d = m ? (int)raw[E + p] : (int)((const unsigned long long*)raw)[E + p];
        atomicAdd(&deg[d], 1);
    }
}

// ---- contention-free degree-bucket ranking (counting sort, hierarchical) ----
__global__ __launch_bounds__(256) void rank_block(const int* __restrict__ deg, float* __restrict__ dinv,
                                                  int* __restrict__ local_rank, int* __restrict__ hist_blk, int N) {
    __shared__ int h[256];
    int t = threadIdx.x;
    h[t] = 0;
    __syncthreads();
    int i = blockIdx.x * 256 + t;
    if (i < N) {
        int d = deg[i];
        dinv[i] = 1.0f / sqrtf((float)(d + 1));   // +1 self-loop
        int b = min(d, 255);
        local_rank[i] = atomicAdd(&h[b], 1);      // LDS atomic: intra-block only
    }
    __syncthreads();
    hist_blk[blockIdx.x * 256 + t] = h[t];
}

__global__ __launch_bounds__(256) void scan_blocks(int* __restrict__ hist_blk, int* __restrict__ binbase,
                                                   int* __restrict__ ebase, int nblk) {
    int b = threadIdx.x;
    int sum = 0;
    int k = 0;
    for (; k + 8 <= nblk; k += 8) {
        int v[8];
        #pragma unroll
        for (int u = 0; u < 8; u++) v[u] = hist_blk[(k + u) * 256 + b];
        #pragma unroll
        for (int u = 0; u < 8; u++) { hist_blk[(k + u) * 256 + b] = sum; sum += v[u]; }
    }
    for (; k < nblk; k++) {
        int v = hist_blk[k * 256 + b];
        hist_blk[k * 256 + b] = sum;
        sum += v;
    }
    __shared__ int s[256], s2[256];
    int c = sum, e = sum * b;
    s[b] = c; s2[b] = e;
    __syncthreads();
    for (int off = 1; off < 256; off <<= 1) {
        int a0 = (b >= off) ? s[b - off] : 0;
        int a1 = (b >= off) ? s2[b - off] : 0;
        __syncthreads();
        s[b] += a0; s2[b] += a1;
        __syncthreads();
    }
    binbase[b] = s[b] - c;
    ebase[b] = s2[b] - e;
}

__global__ __launch_bounds__(256) void emit_perm(const int* __restrict__ deg, const float* __restrict__ dinv,
                                                 const int* __restrict__ local_rank, const int* __restrict__ hist_blk,
                                                 const int* __restrict__ binbase, const int* __restrict__ ebase,
                                                 int* __restrict__ tailcur, int* __restrict__ rowbeg,
                                                 int* __restrict__ cursor, uint4* __restrict__ meta, int N) {
    int i = blockIdx.x * 256 + threadIdx.x;
    if (i >= N) return;
    int d = deg[i];
    int b = min(d, 255);
    int rib = hist_blk[blockIdx.x * 256 + b] + local_rank[i];   // rank within bin
    int pos = binbase[b] + rib;
    int rb = (b < 255) ? (ebase[b] + rib * b) : (ebase[255] + atomicAdd(tailcur, d));
    rowbeg[i] = rb;
    cursor[i] = 0;
    meta[pos] = make_uint4((unsigned)rb, (unsigned)d, __float_as_uint(dinv[i]), (unsigned)i);
}

// ---------------- CSR fill from RAW edges; src fits ushort (N < 65536) ----------------
__global__ __launch_bounds__(256) void fill_csr_raw(const unsigned* __restrict__ raw, const int* __restrict__ gmode,
                                                    const int* __restrict__ rowbeg, int* __restrict__ cursor,
                                                    unsigned short* __restrict__ csr16, int E) {
    int e = blockIdx.x * 256 + threadIdx.x;
    if (e >= E) return;
    int m = *gmode;
    int d = m ? (int)raw[E + e] : (int)((const unsigned long long*)raw)[E + e];
    int s = m ? (int)raw[e]     : (int)((const unsigned long long*)raw)[e];
    int pos = atomicAdd(&cursor[d], 1);
    csr16[rowbeg[d] + pos] = (unsigned short)s;
}

// ---------------- all weights: transpose + split (4 matrices, one dispatch) ----------------
__global__ __launch_bounds__(256) void prep_w_all(const float* __restrict__ Wpre, const float* __restrict__ W1,
                                                  const float* __restrict__ W2, const float* __restrict__ Wpost,
                                                  unsigned short* __restrict__ preh, unsigned short* __restrict__ prel,
                                                  unsigned short* __restrict__ w1h, unsigned short* __restrict__ w1l,
                                                  unsigned short* __restrict__ w2h, unsigned short* __restrict__ w2l,
                                                  unsigned short* __restrict__ poh, unsigned short* __restrict__ pol) {
    int i = blockIdx.x * 256 + threadIdx.x;
    const float* W; unsigned short *wh, *wl; int idx, ncols;
    if (i < 16384)      { W = Wpre;  wh = preh; wl = prel; idx = i;         ncols = 128; }
    else if (i < 32768) { W = W1;    wh = w1h;  wl = w1l;  idx = i - 16384; ncols = 128; }
    else if (i < 49152) { W = W2;    wh = w2h;  wl = w2l;  idx = i - 32768; ncols = 128; }
    else if (i < 55296) { W = Wpost; wh = poh;  wl = pol;  idx = i - 49152; ncols = 40;  }
    else return;
    int n = idx >> 7, k = idx & 127;
    float v = (n < ncols) ? W[k * ncols + n] : 0.f;
    unsigned p = split2p(v);
    wh[idx] = (unsigned short)p;
    wl[idx] = (unsigned short)(p >> 16);
}

// ---------------- bf16x3 MFMA GEMM, software-pipelined, col-halves fused per block ----------------
template<int NTILES, int EPI, int AFMT, int NW>
__global__ __launch_bounds__(NW * 64) void gemm_mfma(const void* __restrict__ Ap,
                                                     const unsigned short* __restrict__ Wth,
                                                     const unsigned short* __restrict__ Wtl,
                                                     const float* __restrict__ bias,
                                                     const float* __restrict__ dinv,
                                                     float* __restrict__ Cf,
                                                     uint32* __restrict__ Pout,
                                                     int nStrips, int N, int outW) {
    int wave = threadIdx.x >> 6;
    int lane = threadIdx.x & 63;
    int l15 = lane & 15, lg = lane >> 4;
    int so, colbase;
    if (NW == 8) { so = wave >> 1; colbase = (wave & 1) * 64; }
    else         { so = wave;      colbase = 0; }
    size_t chunkStride = (size_t)nStrips * 256;   // Npad*16 floats per 16-col chunk

    // persistent B fragments: wt[col][k] contiguous in k -> 16B per lane
    bfrag wh[4][NTILES], wl[4][NTILES];
    #pragma unroll
    for (int ks = 0; ks < 4; ks++)
        #pragma unroll
        for (int nt = 0; nt < NTILES; nt++) {
            size_t off = (size_t)(colbase + nt * 16 + l15) * D + ks * 32 + lg * 8;
            wh[ks][nt] = *(const bfrag*)(Wth + off);
            wl[ks][nt] = *(const bfrag*)(Wtl + off);
        }

    const int stride = gridDim.x * 4;
    int strip = blockIdx.x * 4 + so;
    if (strip >= nStrips) return;

    // raw A staging: 8x uint4 per strip (4 ks x 32B)
    uint4 cur[8];
    auto loadraw = [&](int s, uint4* r) {
        int arow = min(s * 16 + l15, N - 1);
        const uint4* p = (const uint4*)Ap + (size_t)arow * 32 + lg * 2;
        #pragma unroll
        for (int ks = 0; ks < 4; ks++) {
            r[2 * ks]     = p[ks * 8];
            r[2 * ks + 1] = p[ks * 8 + 1];
        }
    };

    loadraw(strip, cur);
    while (true) {
        int next = strip + stride;
        bool has_next = next < nStrips;
        uint4 nxt[8];
        if (has_next) loadraw(next, nxt);   // issue next loads before MFMA

        bfrag ah[4], al[4];
        #pragma unroll
        for (int ks = 0; ks < 4; ks++) {
            if (AFMT == 0) unpair_r(cur[2 * ks], cur[2 * ks + 1], ah[ks], al[ks]);
            else           split8_r(cur[2 * ks], cur[2 * ks + 1], ah[ks], al[ks]);
        }
        f32x4 acc[NTILES];
        #pragma unroll
        for (int nt = 0; nt < NTILES; nt++) acc[nt] = (f32x4){0.f, 0.f, 0.f, 0.f};
        #pragma unroll
        for (int ks = 0; ks < 4; ks++) {
            #pragma unroll
            for (int nt = 0; nt < NTILES; nt++)
                acc[nt] = __builtin_amdgcn_mfma_f32_16x16x32_bf16(ah[ks], wh[ks][nt], acc[nt], 0, 0, 0);
            #pragma unroll
            for (int nt = 0; nt < NTILES; nt++)
                acc[nt] = __builtin_amdgcn_mfma_f32_16x16x32_bf16(ah[ks], wl[ks][nt], acc[nt], 0, 0, 0);
            #pragma unroll
            for (int nt = 0; nt < NTILES; nt++)
                acc[nt] = __builtin_amdgcn_mfma_f32_16x16x32_bf16(al[ks], wh[ks][nt], acc[nt], 0, 0, 0);
        }

        int row0 = strip * 16;
        float dv[4];
        if (EPI == 0) {
            #pragma unroll
            for (int r = 0; r < 4; r++) {
                int row = row0 + lg * 4 + r;
                dv[r] = (row < N) ? dinv[row] : 0.f;
            }
        }
        // C/D layout (m89-verified): col = lane&15, row = (lane>>4)*4 + reg
        #pragma unroll
        for (int nt = 0; nt < NTILES; nt++) {
            int col = colbase + nt * 16 + l15;
            #pragma unroll
            for (int r = 0; r < 4; r++) {
                int row = row0 + lg * 4 + r;
                if (row >= N) continue;
                float v = acc[nt][r];
                if (EPI == 0) {
                    Cf[(size_t)(col >> 4) * chunkStride + (size_t)row * 16 + (col & 15)] = v * dv[r];
                } else if (EPI == 1) {
                    Pout[(size_t)row * D + col] = split2p(v + bias[col]);
                } else {
                    if (col < outW) Cf[(size_t)row * outW + col] = v + bias[col];
                }
            }
        }
        if (!has_next) break;
        #pragma unroll
        for (int i = 0; i < 8; i++) cur[i] = nxt[i];
        strip = next;
    }
}

// ---------------- XCD-pinned chunked gather, degree-sorted, 4-deep edge-way parallel ----------------
__global__ __launch_bounds__(256) void gather_xcd(const unsigned short* __restrict__ csr16,
                                                  const uint4* __restrict__ meta,
                                                  const float* __restrict__ t_c, const float* __restrict__ bias,
                                                  uint32* __restrict__ Pout, int N, int nStrips) {
    int chunk = blockIdx.x & 7;
    int k = (blockIdx.x >> 3) * 16 + (threadIdx.x >> 4);   // sorted position
    if (k >= N) return;
    uint4 m = meta[k];
    int beg = (int)m.x;
    int end = beg + (int)m.y;
    float di = __uint_as_float(m.z);
    int node = (int)m.w;
    int w = (threadIdx.x >> 2) & 3;
    int c = threadIdx.x & 3;
    const float* tc = t_c + (size_t)chunk * nStrips * 256 + c * 4;
    float4 a0 = make_float4(0.f, 0.f, 0.f, 0.f);
    float4 a1 = make_float4(0.f, 0.f, 0.f, 0.f);
    int j = beg + w;
    for (; j + 12 < end; j += 16) {
        int o0 = csr16[j];
        int o1 = csr16[j + 4];
        int o2 = csr16[j + 8];
        int o3 = csr16[j + 12];
        float4 v0 = *(const float4*)(tc + ((size_t)o0 << 4));
        float4 v1 = *(const float4*)(tc + ((size_t)o1 << 4));
        float4 v2 = *(const float4*)(tc + ((size_t)o2 << 4));
        float4 v3 = *(const float4*)(tc + ((size_t)o3 << 4));
        a0.x += v0.x; a0.y += v0.y; a0.z += v0.z; a0.w += v0.w;
        a1.x += v1.x; a1.y += v1.y; a1.z += v1.z; a1.w += v1.w;
        a0.x += v2.x; a0.y += v2.y; a0.z += v2.z; a0.w += v2.w;
        a1.x += v3.x; a1.y += v3.y; a1.z += v3.z; a1.w += v3.w;
    }
    for (; j < end; j += 4) {
        int o0 = csr16[j];
        float4 v0 = *(const float4*)(tc + ((size_t)o0 << 4));
        a0.x += v0.x; a0.y += v0.y; a0.z += v0.z; a0.w += v0.w;
    }
    a0.x += a1.x; a0.y += a1.y; a0.z += a1.z; a0.w += a1.w;
    // combine 4 edge-ways (lane bits 2-3)
    a0.x += __shfl_xor(a0.x, 4); a0.y += __shfl_xor(a0.y, 4);
    a0.z += __shfl_xor(a0.z, 4); a0.w += __shfl_xor(a0.w, 4);
    a0.x += __shfl_xor(a0.x, 8); a0.y += __shfl_xor(a0.y, 8);
    a0.z += __shfl_xor(a0.z, 8); a0.w += __shfl_xor(a0.w, 8);
    if (w != 0) return;
    // t' pre-scaled by dinv: out = dinv[d]*(sum + t'[d]) + b
    float4 tv = *(const float4*)(tc + (size_t)node * 16);
    int col0 = chunk * 16 + c * 4;
    float4 b = *((const float4*)bias + (col0 >> 2));
    float4 r;
    r.x = fmaxf(fmaf(di, a0.x + tv.x, b.x), 0.f);
    r.y = fmaxf(fmaf(di, a0.y + tv.y, b.y), 0.f);
    r.z = fmaxf(fmaf(di, a0.z + tv.z, b.z), 0.f);
    r.w = fmaxf(fmaf(di, a0.w + tv.w, b.w), 0.f);
    uint4 p;
    p.x = split2p(r.x); p.y = split2p(r.y); p.z = split2p(r.z); p.w = split2p(r.w);
    *(uint4*)(Pout + (size_t)node * D + col0) = p;
}

extern "C" void kernel_launch(void* const* d_in, const int* in_sizes, int n_in,
                              void* d_out, int out_size, void* d_ws, size_t ws_size,
                              hipStream_t stream) {
    const float* x      = (const float*)d_in[0];
    const unsigned* edges = (const unsigned*)d_in[1];
    const float* W_pre  = (const float*)d_in[2];
    const float* b_pre  = (const float*)d_in[3];
    const float* W1     = (const float*)d_in[4];
    const float* b1     = (const float*)d_in[5];
    const float* W2     = (const float*)d_in[6];
    const float* b2     = (const float*)d_in[7];
    const float* W_post = (const float*)d_in[8];
    const float* b_post = (const float*)d_in[9];
    float* out = (float*)d_out;

    const int N = in_sizes[0] / D;        // 50000
    const int E = in_sizes[1] / 2;        // 800000
    const int nStrips = (N + 15) / 16;    // 3125
    const int Npad = nStrips * 16;
    const int nBlk = (N + 255) / 256;     // 196

    // ---- workspace layout (persistent buffers) ----
    char* ws = (char*)d_ws;
    size_t off = 0;
    auto alloc = [&](size_t bytes) { void* p = ws + off; off += (bytes + 255) & ~(size_t)255; return p; };
    uint32* pairA = (uint32*)alloc((size_t)Npad * D * 4);   // pair plane A
    uint32* pairB = (uint32*)alloc((size_t)Npad * D * 4);   // pair plane B
    float*  bufT  = (float*)alloc((size_t)Npad * D * 4);    // chunked pre-scaled t'[8][Npad][16]
    float*  dinv    = (float*)alloc((size_t)N * 4);
    int*    deg     = (int*)alloc((size_t)N * 4);
    int*    rowbeg  = (int*)alloc((size_t)N * 4);
    unsigned short* csr16 = (unsigned short*)alloc((size_t)E * 2);
    uint4*  meta    = (uint4*)alloc((size_t)N * 16);
    unsigned short* wpre_h  = (unsigned short*)alloc(128 * 128 * 2);
    unsigned short* wpre_l  = (unsigned short*)alloc(128 * 128 * 2);
    unsigned short* w1_h    = (unsigned short*)alloc(128 * 128 * 2);
    unsigned short* w1_l    = (unsigned short*)alloc(128 * 128 * 2);
    unsigned short* w2_h    = (unsigned short*)alloc(128 * 128 * 2);
    unsigned short* w2_l    = (unsigned short*)alloc(128 * 128 * 2);
    unsigned short* wpost_h = (unsigned short*)alloc(48 * 128 * 2);
    unsigned short* wpost_l = (unsigned short*)alloc(48 * 128 * 2);

    // ---- prep-phase temporaries OVERLAY bufT (dead before first bufT write) ----
    {
        char* t = (char*)bufT;
        size_t toff = 0;
        auto talloc = [&](size_t bytes) { void* p = t + toff; toff += (bytes + 255) & ~(size_t)255; return p; };
        int* cursor     = (int*)talloc((size_t)N * 4);
        int* local_rank = (int*)talloc((size_t)N * 4);
        int* hist_blk   = (int*)talloc((size_t)nBlk * 256 * 4); // ~200 KB
        int* mode2      = (int*)talloc(256);                    // [0]=gmode, [1]=tail cursor
        int* binbase    = (int*)talloc(1024);
        int* ebase      = (int*)talloc(1024);
        int* gmode = mode2;
        int* tailcur = mode2 + 1;

        (void)hipMemsetAsync(mode2, 0, 8, stream);
        (void)hipMemsetAsync(deg, 0, (size_t)N * 4, stream);
        deg_raw<<<(E + 1023) / 1024, 256, 0, stream>>>(edges, deg, gmode, E);
        rank_block<<<nBlk, 256, 0, stream>>>(deg, dinv, local_rank, hist_blk, N);
        scan_blocks<<<1, 256, 0, stream>>>(hist_blk, binbase, ebase, nBlk);
        emit_perm<<<nBlk, 256, 0, stream>>>(deg, dinv, local_rank, hist_blk, binbase, ebase,
                                            tailcur, rowbeg, cursor, meta, N);
        fill_csr_raw<<<(E + 255) / 256, 256, 0, stream>>>(edges, gmode, rowbeg, cursor, csr16, E);
    }

    // weights: transpose + split, one dispatch
    prep_w_all<<<216, 256, 0, stream>>>(W_pre, W1, W2, W_post,
                                        wpre_h, wpre_l, w1_h, w1_l, w2_h, w2_l, wpost_h, wpost_l);

    const int nGatherBlocks = ((N + 15) / 16) * 8;   // 3125 node-blocks x 8 XCD chunks
    const int gemmGrid = 391;   // 1564 strip-slots, 2 strips/slot -> 2x waves vs 196

    // pre MLP: h1(pairB) = x @ W_pre + b_pre  (x split in-register; 512-thr fused col-halves)
    gemm_mfma<4, 1, 1, 8><<<gemmGrid, 512, 0, stream>>>(x, wpre_h, wpre_l, b_pre, nullptr, nullptr, pairB, nStrips, N, D);

    // conv1: t' = dinv*(h1 @ W1) (chunked) ; h2(pairA) = relu(dinv*(gather+self) + b1)
    gemm_mfma<4, 0, 0, 8><<<gemmGrid, 512, 0, stream>>>(pairB, w1_h, w1_l, nullptr, dinv, bufT, nullptr, nStrips, N, D);
    gather_xcd<<<nGatherBlocks, 256, 0, stream>>>(csr16, meta, bufT, b1, pairA, N, nStrips);

    // conv2
    gemm_mfma<4, 0, 0, 8><<<gemmGrid, 512, 0, stream>>>(pairA, w2_h, w2_l, nullptr, dinv, bufT, nullptr, nStrips, N, D);
    gather_xcd<<<nGatherBlocks, 256, 0, stream>>>(csr16, meta, bufT, b2, pairB, N, nStrips);

    // post MLP: out = h3 @ W_post + b_post  (40 cols, padded to 48)
    gemm_mfma<3, 2, 0, 4><<<gemmGrid, 256, 0, stream>>>(pairB, wpost_h, wpost_l, b_post, nullptr, out, nullptr, nStrips, N, 40);
}

// Round 14
// 297.610 us; speedup vs baseline: 1.1140x; 1.1140x over previous
//
#include <hip/hip_runtime.h>

#define D 128

typedef short bfrag __attribute__((ext_vector_type(8)));      // 8 bf16 = 4 VGPRs
typedef float f32x4 __attribute__((ext_vector_type(4)));
typedef unsigned uint32;

// ---------------- bf16 split helpers ----------------
__device__ inline unsigned short bf16_rne(float x) {
    unsigned u = __float_as_uint(x);
    return (unsigned short)((u + 0x7FFFu + ((u >> 16) & 1u)) >> 16);
}
__device__ inline float bf16_to_f(unsigned short h) {
    return __uint_as_float(((unsigned)h) << 16);
}
// pair word: hi in bits [15:0], lo in bits [31:16]
__device__ inline unsigned split2p(float x) {
    unsigned short hi = bf16_rne(x);
    unsigned short lo = bf16_rne(x - bf16_to_f(hi));
    return (unsigned)hi | ((unsigned)lo << 16);
}

// unpack 8 pair-words (2x uint4 regs) -> ah (8 hi bf16), al (8 lo bf16)
__device__ inline void unpair_r(uint4 q0, uint4 q1, bfrag& ah, bfrag& al) {
    union { uint32 u[4]; bfrag b; } H, L;
    H.u[0] = __builtin_amdgcn_perm(q0.y, q0.x, 0x05040100u);
    H.u[1] = __builtin_amdgcn_perm(q0.w, q0.z, 0x05040100u);
    H.u[2] = __builtin_amdgcn_perm(q1.y, q1.x, 0x05040100u);
    H.u[3] = __builtin_amdgcn_perm(q1.w, q1.z, 0x05040100u);
    L.u[0] = __builtin_amdgcn_perm(q0.y, q0.x, 0x07060302u);
    L.u[1] = __builtin_amdgcn_perm(q0.w, q0.z, 0x07060302u);
    L.u[2] = __builtin_amdgcn_perm(q1.y, q1.x, 0x07060302u);
    L.u[3] = __builtin_amdgcn_perm(q1.w, q1.z, 0x07060302u);
    ah = H.b;
    al = L.b;
}

// split 8 fp32 (2x uint4 regs, bit-cast) -> hi/lo bf16 fragments
__device__ inline void split8_r(uint4 q0, uint4 q1, bfrag& ah, bfrag& al) {
    float v[8] = {__uint_as_float(q0.x), __uint_as_float(q0.y), __uint_as_float(q0.z), __uint_as_float(q0.w),
                  __uint_as_float(q1.x), __uint_as_float(q1.y), __uint_as_float(q1.z), __uint_as_float(q1.w)};
    union { unsigned short us[8]; bfrag b; } H, L;
    #pragma unroll
    for (int i = 0; i < 8; i++) {
        unsigned pr = split2p(v[i]);
        H.us[i] = (unsigned short)pr;
        L.us[i] = (unsigned short)(pr >> 16);
    }
    ah = H.b;
    al = L.b;
}

// ---------------- degree from RAW edges + csr sentinel prefill + t' sentinel-row zero ----------------
__global__ __launch_bounds__(256) void deg_raw(const unsigned* __restrict__ raw, int* __restrict__ deg,
                                               int* __restrict__ gmode, unsigned short* __restrict__ csr16,
                                               float* __restrict__ t_c, int E, int N, int csrCap4, int nRows) {
    __shared__ int smode;
    int gid = blockIdx.x * 256 + threadIdx.x;
    int gstride = gridDim.x * 256;
    int p0 = blockIdx.x * 1024;
    if (threadIdx.x < 64) {
        int p = p0 + threadIdx.x * 16;
        unsigned v = (p < E) ? raw[2 * p + 1] : 0u;
        unsigned long long any = __ballot(v != 0u);
        if (threadIdx.x == 0) smode = (any != 0ull) ? 1 : 0;
    }
    __syncthreads();
    int m = smode;
    if (blockIdx.x == 0 && threadIdx.x == 0) *gmode = m;   // all blocks agree
    // prefill csr with sentinel node index N (padded slots read the zero row)
    unsigned short sent = (unsigned short)N;
    ushort4 s4 = make_ushort4(sent, sent, sent, sent);
    for (int i = gid; i < csrCap4; i += gstride) ((ushort4*)csr16)[i] = s4;
    // zero the sentinel rows (row N..nRows-1 of each of the 8 chunks)
    int nSentF4 = 8 * (nRows - N) * 4;   // float4 count
    for (int i = gid; i < nSentF4; i += gstride) {
        int chunk = i / ((nRows - N) * 4);
        int rem = i % ((nRows - N) * 4);
        ((float4*)(t_c + (size_t)chunk * nRows * 16 + (size_t)N * 16))[rem] = make_float4(0.f, 0.f, 0.f, 0.f);
    }
    int pend = min(p0 + 1024, E);
    for (int p = p0 + threadIdx.x; p < pend; p += 256) {
        int d = m ? (int)raw[E + p] : (int)((const unsigned long long*)raw)[E + p];
        atomicAdd(&deg[d], 1);
    }
}

// ---- contention-free degree-bucket ranking (counting sort, hierarchical) ----
__global__ __launch_bounds__(256) void rank_block(const int* __restrict__ deg, float* __restrict__ dinv,
                                                  int* __restrict__ local_rank, int* __restrict__ hist_blk, int N) {
    __shared__ int h[256];
    int t = threadIdx.x;
    h[t] = 0;
    __syncthreads();
    int i = blockIdx.x * 256 + t;
    if (i < N) {
        int d = deg[i];
        dinv[i] = 1.0f / sqrtf((float)(d + 1));   // +1 self-loop
        int b = min(d, 255);
        local_rank[i] = atomicAdd(&h[b], 1);      // LDS atomic: intra-block only
    }
    __syncthreads();
    hist_blk[blockIdx.x * 256 + t] = h[t];
}

// B: scan blocks per bin, then dual LDS scan. ebase uses roundup4(deg) allocation.
__global__ __launch_bounds__(256) void scan_blocks(int* __restrict__ hist_blk, int* __restrict__ binbase,
                                                   int* __restrict__ ebase, int nblk) {
    int b = threadIdx.x;
    int sum = 0;
    int k = 0;
    for (; k + 8 <= nblk; k += 8) {
        int v[8];
        #pragma unroll
        for (int u = 0; u < 8; u++) v[u] = hist_blk[(k + u) * 256 + b];
        #pragma unroll
        for (int u = 0; u < 8; u++) { hist_blk[(k + u) * 256 + b] = sum; sum += v[u]; }
    }
    for (; k < nblk; k++) {
        int v = hist_blk[k * 256 + b];
        hist_blk[k * 256 + b] = sum;
        sum += v;
    }
    __shared__ int s[256], s2[256];
    int bp = (b + 3) & ~3;           // padded per-node edge allocation
    int c = sum, e = sum * bp;
    s[b] = c; s2[b] = e;
    __syncthreads();
    for (int off = 1; off < 256; off <<= 1) {
        int a0 = (b >= off) ? s[b - off] : 0;
        int a1 = (b >= off) ? s2[b - off] : 0;
        __syncthreads();
        s[b] += a0; s2[b] += a1;
        __syncthreads();
    }
    binbase[b] = s[b] - c;
    ebase[b] = s2[b] - e;
}

// C: emit sorted meta + rowbeg; edge allocations padded to multiples of 4 (8B-aligned ushort4)
__global__ __launch_bounds__(256) void emit_perm(const int* __restrict__ deg, const float* __restrict__ dinv,
                                                 const int* __restrict__ local_rank, const int* __restrict__ hist_blk,
                                                 const int* __restrict__ binbase, const int* __restrict__ ebase,
                                                 int* __restrict__ tailcur, int* __restrict__ rowbeg,
                                                 int* __restrict__ cursor, uint4* __restrict__ meta, int N) {
    int i = blockIdx.x * 256 + threadIdx.x;
    if (i >= N) return;
    int d = deg[i];
    int b = min(d, 255);
    int dp = (d + 3) & ~3;
    int rib = hist_blk[blockIdx.x * 256 + b] + local_rank[i];   // rank within bin
    int pos = binbase[b] + rib;
    int rb = (b < 255) ? (ebase[b] + rib * ((b + 3) & ~3)) : (ebase[255] + atomicAdd(tailcur, dp));
    rowbeg[i] = rb;
    cursor[i] = 0;
    meta[pos] = make_uint4((unsigned)rb, (unsigned)dp, __float_as_uint(dinv[i]), (unsigned)i);
}

// ---------------- CSR fill from RAW edges; src fits ushort (N < 65536) ----------------
__global__ __launch_bounds__(256) void fill_csr_raw(const unsigned* __restrict__ raw, const int* __restrict__ gmode,
                                                    const int* __restrict__ rowbeg, int* __restrict__ cursor,
                                                    unsigned short* __restrict__ csr16, int E) {
    int e = blockIdx.x * 256 + threadIdx.x;
    if (e >= E) return;
    int m = *gmode;
    int d = m ? (int)raw[E + e] : (int)((const unsigned long long*)raw)[E + e];
    int s = m ? (int)raw[e]     : (int)((const unsigned long long*)raw)[e];
    int pos = atomicAdd(&cursor[d], 1);
    csr16[rowbeg[d] + pos] = (unsigned short)s;
}

// ---------------- all weights: transpose + split (4 matrices, one dispatch) ----------------
__global__ __launch_bounds__(256) void prep_w_all(const float* __restrict__ Wpre, const float* __restrict__ W1,
                                                  const float* __restrict__ W2, const float* __restrict__ Wpost,
                                                  unsigned short* __restrict__ preh, unsigned short* __restrict__ prel,
                                                  unsigned short* __restrict__ w1h, unsigned short* __restrict__ w1l,
                                                  unsigned short* __restrict__ w2h, unsigned short* __restrict__ w2l,
                                                  unsigned short* __restrict__ poh, unsigned short* __restrict__ pol) {
    int i = blockIdx.x * 256 + threadIdx.x;
    const float* W; unsigned short *wh, *wl; int idx, ncols;
    if (i < 16384)      { W = Wpre;  wh = preh; wl = prel; idx = i;         ncols = 128; }
    else if (i < 32768) { W = W1;    wh = w1h;  wl = w1l;  idx = i - 16384; ncols = 128; }
    else if (i < 49152) { W = W2;    wh = w2h;  wl = w2l;  idx = i - 32768; ncols = 128; }
    else if (i < 55296) { W = Wpost; wh = poh;  wl = pol;  idx = i - 49152; ncols = 40;  }
    else return;
    int n = idx >> 7, k = idx & 127;
    float v = (n < ncols) ? W[k * ncols + n] : 0.f;
    unsigned p = split2p(v);
    wh[idx] = (unsigned short)p;
    wl[idx] = (unsigned short)(p >> 16);
}

// ---------------- bf16x3 MFMA GEMM, software-pipelined, col-halves fused per block ----------------
template<int NTILES, int EPI, int AFMT, int NW>
__global__ __launch_bounds__(NW * 64) void gemm_mfma(const void* __restrict__ Ap,
                                                     const unsigned short* __restrict__ Wth,
                                                     const unsigned short* __restrict__ Wtl,
                                                     const float* __restrict__ bias,
                                                     const float* __restrict__ dinv,
                                                     float* __restrict__ Cf,
                                                     uint32* __restrict__ Pout,
                                                     int nStrips, int N, int outW, int nRows) {
    int wave = threadIdx.x >> 6;
    int lane = threadIdx.x & 63;
    int l15 = lane & 15, lg = lane >> 4;
    int so, colbase;
    if (NW == 8) { so = wave >> 1; colbase = (wave & 1) * 64; }
    else         { so = wave;      colbase = 0; }
    size_t chunkStride = (size_t)nRows * 16;   // floats per 16-col chunk

    // persistent B fragments: wt[col][k] contiguous in k -> 16B per lane
    bfrag wh[4][NTILES], wl[4][NTILES];
    #pragma unroll
    for (int ks = 0; ks < 4; ks++)
        #pragma unroll
        for (int nt = 0; nt < NTILES; nt++) {
            size_t off = (size_t)(colbase + nt * 16 + l15) * D + ks * 32 + lg * 8;
            wh[ks][nt] = *(const bfrag*)(Wth + off);
            wl[ks][nt] = *(const bfrag*)(Wtl + off);
        }

    const int stride = gridDim.x * 4;
    int strip = blockIdx.x * 4 + so;
    if (strip >= nStrips) return;

    // raw A staging: 8x uint4 per strip (4 ks x 32B)
    uint4 cur[8];
    auto loadraw = [&](int s, uint4* r) {
        int arow = min(s * 16 + l15, N - 1);
        const uint4* p = (const uint4*)Ap + (size_t)arow * 32 + lg * 2;
        #pragma unroll
        for (int ks = 0; ks < 4; ks++) {
            r[2 * ks]     = p[ks * 8];
            r[2 * ks + 1] = p[ks * 8 + 1];
        }
    };

    loadraw(strip, cur);
    while (true) {
        int next = strip + stride;
        bool has_next = next < nStrips;
        uint4 nxt[8];
        if (has_next) loadraw(next, nxt);   // issue next loads before MFMA

        bfrag ah[4], al[4];
        #pragma unroll
        for (int ks = 0; ks < 4; ks++) {
            if (AFMT == 0) unpair_r(cur[2 * ks], cur[2 * ks + 1], ah[ks], al[ks]);
            else           split8_r(cur[2 * ks], cur[2 * ks + 1], ah[ks], al[ks]);
        }
        f32x4 acc[NTILES];
        #pragma unroll
        for (int nt = 0; nt < NTILES; nt++) acc[nt] = (f32x4){0.f, 0.f, 0.f, 0.f};
        #pragma unroll
        for (int ks = 0; ks < 4; ks++) {
            #pragma unroll
            for (int nt = 0; nt < NTILES; nt++)
                acc[nt] = __builtin_amdgcn_mfma_f32_16x16x32_bf16(ah[ks], wh[ks][nt], acc[nt], 0, 0, 0);
            #pragma unroll
            for (int nt = 0; nt < NTILES; nt++)
                acc[nt] = __builtin_amdgcn_mfma_f32_16x16x32_bf16(ah[ks], wl[ks][nt], acc[nt], 0, 0, 0);
            #pragma unroll
            for (int nt = 0; nt < NTILES; nt++)
                acc[nt] = __builtin_amdgcn_mfma_f32_16x16x32_bf16(al[ks], wh[ks][nt], acc[nt], 0, 0, 0);
        }

        int row0 = strip * 16;
        float dv[4];
        if (EPI == 0) {
            #pragma unroll
            for (int r = 0; r < 4; r++) {
                int row = row0 + lg * 4 + r;
                dv[r] = (row < N) ? dinv[row] : 0.f;
            }
        }
        // C/D layout (m89-verified): col = lane&15, row = (lane>>4)*4 + reg
        #pragma unroll
        for (int nt = 0; nt < NTILES; nt++) {
            int col = colbase + nt * 16 + l15;
            #pragma unroll
            for (int r = 0; r < 4; r++) {
                int row = row0 + lg * 4 + r;
                if (row >= N) continue;
                float v = acc[nt][r];
                if (EPI == 0) {
                    Cf[(size_t)(col >> 4) * chunkStride + (size_t)row * 16 + (col & 15)] = v * dv[r];
                } else if (EPI == 1) {
                    Pout[(size_t)row * D + col] = split2p(v + bias[col]);
                } else {
                    if (col < outW) Cf[(size_t)row * outW + col] = v + bias[col];
                }
            }
        }
        if (!has_next) break;
        #pragma unroll
        for (int i = 0; i < 8; i++) cur[i] = nxt[i];
        strip = next;
    }
}

// ---------------- XCD-pinned chunked gather, degree-sorted, contiguous-way ushort4 CSR ----------------
// chunk = blockIdx.x & 7 pins a contiguous ~3.2MB pre-scaled slice t'[chunk] to one XCD's L2.
// Edge allocations padded to x4 with sentinel (zero row) -> branchless loop, one ushort4/4 edges.
__global__ __launch_bounds__(256) void gather_xcd(const unsigned short* __restrict__ csr16,
                                                  const uint4* __restrict__ meta,
                                                  const float* __restrict__ t_c, const float* __restrict__ bias,
                                                  uint32* __restrict__ Pout, int N, int nRows) {
    int chunk = blockIdx.x & 7;
    int k = (blockIdx.x >> 3) * 16 + (threadIdx.x >> 4);   // sorted position
    if (k >= N) return;
    uint4 m = meta[k];
    int beg = (int)m.x;
    int degp = (int)m.y;                                   // padded to multiple of 4
    float di = __uint_as_float(m.z);
    int node = (int)m.w;
    int w = (threadIdx.x >> 2) & 3;
    int c = threadIdx.x & 3;
    const float* tc = t_c + (size_t)chunk * nRows * 16 + c * 4;
    float4 a0 = make_float4(0.f, 0.f, 0.f, 0.f);
    float4 a1 = make_float4(0.f, 0.f, 0.f, 0.f);
    float4 a2 = make_float4(0.f, 0.f, 0.f, 0.f);
    float4 a3 = make_float4(0.f, 0.f, 0.f, 0.f);
    int end = beg + degp;
    for (int j = beg + 4 * w; j < end; j += 16) {
        ushort4 o = *(const ushort4*)(csr16 + j);          // 8B-aligned by construction
        float4 v0 = *(const float4*)(tc + ((size_t)o.x << 4));
        float4 v1 = *(const float4*)(tc + ((size_t)o.y << 4));
        float4 v2 = *(const float4*)(tc + ((size_t)o.z << 4));
        float4 v3 = *(const float4*)(tc + ((size_t)o.w << 4));
        a0.x += v0.x; a0.y += v0.y; a0.z += v0.z; a0.w += v0.w;
        a1.x += v1.x; a1.y += v1.y; a1.z += v1.z; a1.w += v1.w;
        a2.x += v2.x; a2.y += v2.y; a2.z += v2.z; a2.w += v2.w;
        a3.x += v3.x; a3.y += v3.y; a3.z += v3.z; a3.w += v3.w;
    }
    a0.x += a1.x; a0.y += a1.y; a0.z += a1.z; a0.w += a1.w;
    a2.x += a3.x; a2.y += a3.y; a2.z += a3.z; a2.w += a3.w;
    a0.x += a2.x; a0.y += a2.y; a0.z += a2.z; a0.w += a2.w;
    // combine 4 edge-ways (lane bits 2-3)
    a0.x += __shfl_xor(a0.x, 4); a0.y += __shfl_xor(a0.y, 4);
    a0.z += __shfl_xor(a0.z, 4); a0.w += __shfl_xor(a0.w, 4);
    a0.x += __shfl_xor(a0.x, 8); a0.y += __shfl_xor(a0.y, 8);
    a0.z += __shfl_xor(a0.z, 8); a0.w += __shfl_xor(a0.w, 8);
    if (w != 0) return;
    // t' pre-scaled by dinv: out = dinv[d]*(sum + t'[d]) + b
    float4 tv = *(const float4*)(tc + (size_t)node * 16);
    int col0 = chunk * 16 + c * 4;
    float4 b = *((const float4*)bias + (col0 >> 2));
    float4 r;
    r.x = fmaxf(fmaf(di, a0.x + tv.x, b.x), 0.f);
    r.y = fmaxf(fmaf(di, a0.y + tv.y, b.y), 0.f);
    r.z = fmaxf(fmaf(di, a0.z + tv.z, b.z), 0.f);
    r.w = fmaxf(fmaf(di, a0.w + tv.w, b.w), 0.f);
    uint4 p;
    p.x = split2p(r.x); p.y = split2p(r.y); p.z = split2p(r.z); p.w = split2p(r.w);
    *(uint4*)(Pout + (size_t)node * D + col0) = p;
}

extern "C" void kernel_launch(void* const* d_in, const int* in_sizes, int n_in,
                              void* d_out, int out_size, void* d_ws, size_t ws_size,
                              hipStream_t stream) {
    const float* x      = (const float*)d_in[0];
    const unsigned* edges = (const unsigned*)d_in[1];
    const float* W_pre  = (const float*)d_in[2];
    const float* b_pre  = (const float*)d_in[3];
    const float* W1     = (const float*)d_in[4];
    const float* b1     = (const float*)d_in[5];
    const float* W2     = (const float*)d_in[6];
    const float* b2     = (const float*)d_in[7];
    const float* W_post = (const float*)d_in[8];
    const float* b_post = (const float*)d_in[9];
    float* out = (float*)d_out;

    const int N = in_sizes[0] / D;        // 50000
    const int E = in_sizes[1] / 2;        // 800000
    const int nStrips = (N + 15) / 16;    // 3125
    const int Npad = nStrips * 16;
    const int nRows = Npad + 16;          // + sentinel rows (row N is the zero row)
    const int nBlk = (N + 255) / 256;     // 196
    const int csrCap = (E + 4 * N + 255) & ~255;   // padded csr capacity (shorts)

    // ---- workspace layout (persistent buffers) ----
    char* ws = (char*)d_ws;
    size_t off = 0;
    auto alloc = [&](size_t bytes) { void* p = ws + off; off += (bytes + 255) & ~(size_t)255; return p; };
    uint32* pairA = (uint32*)alloc((size_t)Npad * D * 4);   // pair plane A
    uint32* pairB = (uint32*)alloc((size_t)Npad * D * 4);   // pair plane B
    float*  bufT  = (float*)alloc((size_t)8 * nRows * 16 * 4);   // chunked pre-scaled t'[8][nRows][16]
    float*  dinv    = (float*)alloc((size_t)N * 4);
    int*    deg     = (int*)alloc((size_t)N * 4);
    int*    rowbeg  = (int*)alloc((size_t)N * 4);
    unsigned short* csr16 = (unsigned short*)alloc((size_t)csrCap * 2);
    uint4*  meta    = (uint4*)alloc((size_t)N * 16);
    unsigned short* wpre_h  = (unsigned short*)alloc(128 * 128 * 2);
    unsigned short* wpre_l  = (unsigned short*)alloc(128 * 128 * 2);
    unsigned short* w1_h    = (unsigned short*)alloc(128 * 128 * 2);
    unsigned short* w1_l    = (unsigned short*)alloc(128 * 128 * 2);
    unsigned short* w2_h    = (unsigned short*)alloc(128 * 128 * 2);
    unsigned short* w2_l    = (unsigned short*)alloc(128 * 128 * 2);
    unsigned short* wpost_h = (unsigned short*)alloc(48 * 128 * 2);
    unsigned short* wpost_l = (unsigned short*)alloc(48 * 128 * 2);

    // ---- prep-phase temporaries OVERLAY bufT (first ~1 MB; sentinel rows are beyond 3 MB) ----
    {
        char* t = (char*)bufT;
        size_t toff = 0;
        auto talloc = [&](size_t bytes) { void* p = t + toff; toff += (bytes + 255) & ~(size_t)255; return p; };
        int* cursor     = (int*)talloc((size_t)N * 4);
        int* local_rank = (int*)talloc((size_t)N * 4);
        int* hist_blk   = (int*)talloc((size_t)nBlk * 256 * 4); // ~200 KB
        int* mode2      = (int*)talloc(256);                    // [0]=gmode, [1]=tail cursor
        int* binbase    = (int*)talloc(1024);
        int* ebase      = (int*)talloc(1024);
        int* gmode = mode2;
        int* tailcur = mode2 + 1;

        (void)hipMemsetAsync(mode2, 0, 8, stream);
        (void)hipMemsetAsync(deg, 0, (size_t)N * 4, stream);
        deg_raw<<<(E + 1023) / 1024, 256, 0, stream>>>(edges, deg, gmode, csr16, bufT, E, N, csrCap / 4, nRows);
        rank_block<<<nBlk, 256, 0, stream>>>(deg, dinv, local_rank, hist_blk, N);
        scan_blocks<<<1, 256, 0, stream>>>(hist_blk, binbase, ebase, nBlk);
        emit_perm<<<nBlk, 256, 0, stream>>>(deg, dinv, local_rank, hist_blk, binbase, ebase,
                                            tailcur, rowbeg, cursor, meta, N);
        fill_csr_raw<<<(E + 255) / 256, 256, 0, stream>>>(edges, gmode, rowbeg, cursor, csr16, E);
    }

    // weights: transpose + split, one dispatch
    prep_w_all<<<216, 256, 0, stream>>>(W_pre, W1, W2, W_post,
                                        wpre_h, wpre_l, w1_h, w1_l, w2_h, w2_l, wpost_h, wpost_l);

    const int nGatherBlocks = ((N + 15) / 16) * 8;   // 3125 node-blocks x 8 XCD chunks
    const int gemmGrid = 256;   // exactly one block per CU: full machine, single scheduling round

    // pre MLP: h1(pairB) = x @ W_pre + b_pre  (x split in-register; 512-thr fused col-halves)
    gemm_mfma<4, 1, 1, 8><<<gemmGrid, 512, 0, stream>>>(x, wpre_h, wpre_l, b_pre, nullptr, nullptr, pairB, nStrips, N, D, nRows);

    // conv1: t' = dinv*(h1 @ W1) (chunked) ; h2(pairA) = relu(dinv*(gather+self) + b1)
    gemm_mfma<4, 0, 0, 8><<<gemmGrid, 512, 0, stream>>>(pairB, w1_h, w1_l, nullptr, dinv, bufT, nullptr, nStrips, N, D, nRows);
    gather_xcd<<<nGatherBlocks, 256, 0, stream>>>(csr16, meta, bufT, b1, pairA, N, nRows);

    // conv2
    gemm_mfma<4, 0, 0, 8><<<gemmGrid, 512, 0, stream>>>(pairA, w2_h, w2_l, nullptr, dinv, bufT, nullptr, nStrips, N, D, nRows);
    gather_xcd<<<nGatherBlocks, 256, 0, stream>>>(csr16, meta, bufT, b2, pairB, N, nRows);

    // post MLP: out = h3 @ W_post + b_post  (40 cols, padded to 48)
    gemm_mfma<3, 2, 0, 4><<<gemmGrid, 256, 0, stream>>>(pairB, wpost_h, wpost_l, b_post, nullptr, out, nullptr, nStrips, N, 40, nRows);
}

// Round 15
// 267.280 us; speedup vs baseline: 1.2404x; 1.1135x over previous
//
#include <hip/hip_runtime.h>

#define D 128

typedef short bfrag __attribute__((ext_vector_type(8)));      // 8 bf16 = 4 VGPRs
typedef float f32x4 __attribute__((ext_vector_type(4)));
typedef unsigned uint32;

// ---------------- bf16 split helpers ----------------
__device__ inline unsigned short bf16_rne(float x) {
    unsigned u = __float_as_uint(x);
    return (unsigned short)((u + 0x7FFFu + ((u >> 16) & 1u)) >> 16);
}
__device__ inline float bf16_to_f(unsigned short h) {
    return __uint_as_float(((unsigned)h) << 16);
}
// pair word: hi in bits [15:0], lo in bits [31:16]
__device__ inline unsigned split2p(float x) {
    unsigned short hi = bf16_rne(x);
    unsigned short lo = bf16_rne(x - bf16_to_f(hi));
    return (unsigned)hi | ((unsigned)lo << 16);
}

// unpack 8 pair-words (2x uint4 regs) -> ah (8 hi bf16), al (8 lo bf16)
__device__ inline void unpair_r(uint4 q0, uint4 q1, bfrag& ah, bfrag& al) {
    union { uint32 u[4]; bfrag b; } H, L;
    H.u[0] = __builtin_amdgcn_perm(q0.y, q0.x, 0x05040100u);
    H.u[1] = __builtin_amdgcn_perm(q0.w, q0.z, 0x05040100u);
    H.u[2] = __builtin_amdgcn_perm(q1.y, q1.x, 0x05040100u);
    H.u[3] = __builtin_amdgcn_perm(q1.w, q1.z, 0x05040100u);
    L.u[0] = __builtin_amdgcn_perm(q0.y, q0.x, 0x07060302u);
    L.u[1] = __builtin_amdgcn_perm(q0.w, q0.z, 0x07060302u);
    L.u[2] = __builtin_amdgcn_perm(q1.y, q1.x, 0x07060302u);
    L.u[3] = __builtin_amdgcn_perm(q1.w, q1.z, 0x07060302u);
    ah = H.b;
    al = L.b;
}

// split 8 fp32 (2x uint4 regs, bit-cast) -> hi/lo bf16 fragments
__device__ inline void split8_r(uint4 q0, uint4 q1, bfrag& ah, bfrag& al) {
    float v[8] = {__uint_as_float(q0.x), __uint_as_float(q0.y), __uint_as_float(q0.z), __uint_as_float(q0.w),
                  __uint_as_float(q1.x), __uint_as_float(q1.y), __uint_as_float(q1.z), __uint_as_float(q1.w)};
    union { unsigned short us[8]; bfrag b; } H, L;
    #pragma unroll
    for (int i = 0; i < 8; i++) {
        unsigned pr = split2p(v[i]);
        H.us[i] = (unsigned short)pr;
        L.us[i] = (unsigned short)(pr >> 16);
    }
    ah = H.b;
    al = L.b;
}

// ---------------- degree from RAW edges + csr sentinel prefill + t' sentinel zero + W prep ----------------
__global__ __launch_bounds__(256) void deg_raw(const unsigned* __restrict__ raw, int* __restrict__ deg,
                                               int* __restrict__ gmode, unsigned short* __restrict__ csr16,
                                               float* __restrict__ t_c, int E, int Npad, int csrCap4, int nRows,
                                               const float* __restrict__ Wpre, const float* __restrict__ W1,
                                               const float* __restrict__ W2, const float* __restrict__ Wpost,
                                               uint32* __restrict__ wpre_p, uint32* __restrict__ w1_p,
                                               uint32* __restrict__ w2_p, uint32* __restrict__ wpost_p) {
    __shared__ int smode;
    int gid = blockIdx.x * 256 + threadIdx.x;
    int gstride = gridDim.x * 256;
    int p0 = blockIdx.x * 1024;
    if (threadIdx.x < 64) {
        int p = p0 + threadIdx.x * 16;
        unsigned v = (p < E) ? raw[2 * p + 1] : 0u;
        unsigned long long any = __ballot(v != 0u);
        if (threadIdx.x == 0) smode = (any != 0ull) ? 1 : 0;
    }
    __syncthreads();
    int m = smode;
    if (blockIdx.x == 0 && threadIdx.x == 0) *gmode = m;   // all blocks agree
    // prefill csr with sentinel node index Npad (padded slots read the zero row)
    unsigned short sent = (unsigned short)Npad;
    ushort4 s4 = make_ushort4(sent, sent, sent, sent);
    for (int i = gid; i < csrCap4; i += gstride) ((ushort4*)csr16)[i] = s4;
    // zero the sentinel rows (row Npad..nRows-1 of each of the 8 chunks)
    int sentRows = nRows - Npad;
    int nSentF4 = 8 * sentRows * 4;   // float4 count
    for (int i = gid; i < nSentF4; i += gstride) {
        int chunk = i / (sentRows * 4);
        int rem = i % (sentRows * 4);
        ((float4*)(t_c + (size_t)chunk * nRows * 16 + (size_t)Npad * 16))[rem] = make_float4(0.f, 0.f, 0.f, 0.f);
    }
    // weight transpose + pair-pack (all 4 matrices)
    for (int i = gid; i < 55296; i += gstride) {
        const float* W; uint32* wp; int idx, ncols;
        if (i < 16384)      { W = Wpre;  wp = wpre_p;  idx = i;         ncols = 128; }
        else if (i < 32768) { W = W1;    wp = w1_p;    idx = i - 16384; ncols = 128; }
        else if (i < 49152) { W = W2;    wp = w2_p;    idx = i - 32768; ncols = 128; }
        else                { W = Wpost; wp = wpost_p; idx = i - 49152; ncols = 40;  }
        int n = idx >> 7, k = idx & 127;
        float v = (n < ncols) ? W[k * ncols + n] : 0.f;
        wp[idx] = split2p(v);
    }
    int pend = min(p0 + 1024, E);
    for (int p = p0 + threadIdx.x; p < pend; p += 256) {
        int d = m ? (int)raw[E + p] : (int)((const unsigned long long*)raw)[E + p];
        atomicAdd(&deg[d], 1);
    }
}

// ---- contention-free degree-bucket ranking (counting sort, hierarchical) ----
__global__ __launch_bounds__(256) void rank_block(const int* __restrict__ deg, float* __restrict__ dinv,
                                                  int* __restrict__ local_rank, int* __restrict__ hist_blk, int N) {
    __shared__ int h[256];
    int t = threadIdx.x;
    h[t] = 0;
    __syncthreads();
    int i = blockIdx.x * 256 + t;
    if (i < N) {
        int d = deg[i];
        dinv[i] = 1.0f / sqrtf((float)(d + 1));   // +1 self-loop
        int b = min(d, 255);
        local_rank[i] = atomicAdd(&h[b], 1);      // LDS atomic: intra-block only
    }
    __syncthreads();
    hist_blk[blockIdx.x * 256 + t] = h[t];
}

// B: scan blocks per bin, then dual LDS scan. ebase uses roundup4(deg) allocation.
__global__ __launch_bounds__(256) void scan_blocks(int* __restrict__ hist_blk, int* __restrict__ binbase,
                                                   int* __restrict__ ebase, int nblk) {
    int b = threadIdx.x;
    int sum = 0;
    int k = 0;
    for (; k + 8 <= nblk; k += 8) {
        int v[8];
        #pragma unroll
        for (int u = 0; u < 8; u++) v[u] = hist_blk[(k + u) * 256 + b];
        #pragma unroll
        for (int u = 0; u < 8; u++) { hist_blk[(k + u) * 256 + b] = sum; sum += v[u]; }
    }
    for (; k < nblk; k++) {
        int v = hist_blk[k * 256 + b];
        hist_blk[k * 256 + b] = sum;
        sum += v;
    }
    __shared__ int s[256], s2[256];
    int bp = (b + 3) & ~3;           // padded per-node edge allocation
    int c = sum, e = sum * bp;
    s[b] = c; s2[b] = e;
    __syncthreads();
    for (int off = 1; off < 256; off <<= 1) {
        int a0 = (b >= off) ? s[b - off] : 0;
        int a1 = (b >= off) ? s2[b - off] : 0;
        __syncthreads();
        s[b] += a0; s2[b] += a1;
        __syncthreads();
    }
    binbase[b] = s[b] - c;
    ebase[b] = s2[b] - e;
}

// C: emit sorted meta + rowbeg; edge allocations padded to multiples of 4 (8B-aligned ushort4)
__global__ __launch_bounds__(256) void emit_perm(const int* __restrict__ deg, const float* __restrict__ dinv,
                                                 const int* __restrict__ local_rank, const int* __restrict__ hist_blk,
                                                 const int* __restrict__ binbase, const int* __restrict__ ebase,
                                                 int* __restrict__ tailcur, int* __restrict__ rowbeg,
                                                 int* __restrict__ cursor, uint4* __restrict__ meta, int N) {
    int i = blockIdx.x * 256 + threadIdx.x;
    if (i >= N) return;
    int d = deg[i];
    int b = min(d, 255);
    int dp = (d + 3) & ~3;
    int rib = hist_blk[blockIdx.x * 256 + b] + local_rank[i];   // rank within bin
    int pos = binbase[b] + rib;
    int rb = (b < 255) ? (ebase[b] + rib * ((b + 3) & ~3)) : (ebase[255] + atomicAdd(tailcur, dp));
    rowbeg[i] = rb;
    cursor[i] = 0;
    meta[pos] = make_uint4((unsigned)rb, (unsigned)dp, __float_as_uint(dinv[i]), (unsigned)i);
}

// ---------------- CSR fill from RAW edges; src fits ushort (N < 65536) ----------------
__global__ __launch_bounds__(256) void fill_csr_raw(const unsigned* __restrict__ raw, const int* __restrict__ gmode,
                                                    const int* __restrict__ rowbeg, int* __restrict__ cursor,
                                                    unsigned short* __restrict__ csr16, int E) {
    int e = blockIdx.x * 256 + threadIdx.x;
    if (e >= E) return;
    int m = *gmode;
    int d = m ? (int)raw[E + e] : (int)((const unsigned long long*)raw)[E + e];
    int s = m ? (int)raw[e]     : (int)((const unsigned long long*)raw)[e];
    int pos = atomicAdd(&cursor[d], 1);
    csr16[rowbeg[d] + pos] = (unsigned short)s;
}

// ---------------- bf16x3 MFMA GEMM with W in LDS (pair-packed, padded) ----------------
// 512 threads, 8 waves: wave w -> strip-slot w>>1, col-half (w&1)*64. W staged once into
// LDS [128][132] u32 (+4 pad word -> 2-way bank aliasing, free). ~115 VGPR -> 4 waves/SIMD.
// AFMT=0: A pair plane. AFMT=1: A fp32 (split in-register).
// EPI=0: Cf fp32 CHUNKED t'[chunk][row][16] PRE-SCALED by dinv[row].  EPI=1: bias -> pair Pout.
template<int EPI, int AFMT>
__global__ __launch_bounds__(512) void gemm_lds(const void* __restrict__ Ap,
                                                const uint32* __restrict__ Wpair,
                                                const float* __restrict__ bias,
                                                const float* __restrict__ dinv,
                                                float* __restrict__ Cf,
                                                uint32* __restrict__ Pout,
                                                int nStrips, int N, int nRows) {
    __shared__ uint32 Wl[128 * 132];
    int tid = threadIdx.x;
    for (int i = tid; i < 16384; i += 512)
        Wl[(i >> 7) * 132 + (i & 127)] = Wpair[i];
    __syncthreads();

    int wave = tid >> 6;
    int lane = tid & 63;
    int l15 = lane & 15, lg = lane >> 4;
    int so = wave >> 1;
    int colbase = (wave & 1) * 64;
    size_t chunkStride = (size_t)nRows * 16;

    const int stride = gridDim.x * 4;
    for (int strip = blockIdx.x * 4 + so; strip < nStrips; strip += stride) {
        int arow = min(strip * 16 + l15, N - 1);
        uint4 cur[8];
        const uint4* p = (const uint4*)Ap + (size_t)arow * 32 + lg * 2;
        #pragma unroll
        for (int ks = 0; ks < 4; ks++) {
            cur[2 * ks]     = p[ks * 8];
            cur[2 * ks + 1] = p[ks * 8 + 1];
        }
        bfrag ah[4], al[4];
        #pragma unroll
        for (int ks = 0; ks < 4; ks++) {
            if (AFMT == 0) unpair_r(cur[2 * ks], cur[2 * ks + 1], ah[ks], al[ks]);
            else           split8_r(cur[2 * ks], cur[2 * ks + 1], ah[ks], al[ks]);
        }
        f32x4 acc[4];
        #pragma unroll
        for (int nt = 0; nt < 4; nt++) acc[nt] = (f32x4){0.f, 0.f, 0.f, 0.f};
        #pragma unroll
        for (int ks = 0; ks < 4; ks++) {
            #pragma unroll
            for (int nt = 0; nt < 4; nt++) {
                const uint32* wp = &Wl[(colbase + nt * 16 + l15) * 132 + ks * 32 + lg * 8];
                uint4 w0 = *(const uint4*)wp;
                uint4 w1 = *(const uint4*)(wp + 4);
                bfrag wh, wl_;
                unpair_r(w0, w1, wh, wl_);
                acc[nt] = __builtin_amdgcn_mfma_f32_16x16x32_bf16(ah[ks], wh, acc[nt], 0, 0, 0);
                acc[nt] = __builtin_amdgcn_mfma_f32_16x16x32_bf16(ah[ks], wl_, acc[nt], 0, 0, 0);
                acc[nt] = __builtin_amdgcn_mfma_f32_16x16x32_bf16(al[ks], wh, acc[nt], 0, 0, 0);
            }
        }
        int row0 = strip * 16;
        // C/D layout (m89-verified): col = lane&15, row = (lane>>4)*4 + reg
        if (EPI == 0) {
            float dv[4];
            #pragma unroll
            for (int r = 0; r < 4; r++) dv[r] = dinv[min(row0 + lg * 4 + r, N - 1)];
            #pragma unroll
            for (int nt = 0; nt < 4; nt++) {
                int col = colbase + nt * 16 + l15;
                float* cbase = Cf + (size_t)(col >> 4) * chunkStride + (col & 15);
                #pragma unroll
                for (int r = 0; r < 4; r++)
                    cbase[(size_t)(row0 + lg * 4 + r) * 16] = acc[nt][r] * dv[r];
            }
        } else {
            #pragma unroll
            for (int nt = 0; nt < 4; nt++) {
                int col = colbase + nt * 16 + l15;
                float bv = bias[col];
                #pragma unroll
                for (int r = 0; r < 4; r++)
                    Pout[(size_t)(row0 + lg * 4 + r) * D + col] = split2p(acc[nt][r] + bv);
            }
        }
    }
}

// ---------------- post GEMM (register-W, pair-packed source): out = h3 @ W_post + b ----------------
__global__ __launch_bounds__(256) void gemm_post(const uint32* __restrict__ P,
                                                 const uint32* __restrict__ Wpair,
                                                 const float* __restrict__ bias,
                                                 float* __restrict__ Cf,
                                                 int nStrips, int N, int outW) {
    int wave = threadIdx.x >> 6;
    int lane = threadIdx.x & 63;
    int l15 = lane & 15, lg = lane >> 4;

    bfrag wh[4][3], wl[4][3];
    #pragma unroll
    for (int ks = 0; ks < 4; ks++)
        #pragma unroll
        for (int nt = 0; nt < 3; nt++) {
            const uint32* wp = Wpair + (size_t)(nt * 16 + l15) * D + ks * 32 + lg * 8;
            uint4 w0 = *(const uint4*)wp;
            uint4 w1 = *(const uint4*)(wp + 4);
            unpair_r(w0, w1, wh[ks][nt], wl[ks][nt]);
        }

    const int stride = gridDim.x * 4;
    for (int strip = blockIdx.x * 4 + wave; strip < nStrips; strip += stride) {
        int arow = min(strip * 16 + l15, N - 1);
        bfrag ah[4], al[4];
        #pragma unroll
        for (int ks = 0; ks < 4; ks++) {
            const uint4* p = (const uint4*)P + (size_t)arow * 32 + lg * 2;
            unpair_r(p[ks * 8], p[ks * 8 + 1], ah[ks], al[ks]);
        }
        f32x4 acc[3];
        #pragma unroll
        for (int nt = 0; nt < 3; nt++) acc[nt] = (f32x4){0.f, 0.f, 0.f, 0.f};
        #pragma unroll
        for (int ks = 0; ks < 4; ks++)
            #pragma unroll
            for (int nt = 0; nt < 3; nt++) {
                acc[nt] = __builtin_amdgcn_mfma_f32_16x16x32_bf16(ah[ks], wh[ks][nt], acc[nt], 0, 0, 0);
                acc[nt] = __builtin_amdgcn_mfma_f32_16x16x32_bf16(ah[ks], wl[ks][nt], acc[nt], 0, 0, 0);
                acc[nt] = __builtin_amdgcn_mfma_f32_16x16x32_bf16(al[ks], wh[ks][nt], acc[nt], 0, 0, 0);
            }
        int row0 = strip * 16;
        #pragma unroll
        for (int nt = 0; nt < 3; nt++) {
            int col = nt * 16 + l15;
            #pragma unroll
            for (int r = 0; r < 4; r++) {
                int row = row0 + lg * 4 + r;
                if (row < N && col < outW)
                    Cf[(size_t)row * outW + col] = acc[nt][r] + bias[col];
            }
        }
    }
}

// ---------------- XCD-pinned chunked gather, degree-sorted, contiguous-way ushort4 CSR ----------------
__global__ __launch_bounds__(256) void gather_xcd(const unsigned short* __restrict__ csr16,
                                                  const uint4* __restrict__ meta,
                                                  const float* __restrict__ t_c, const float* __restrict__ bias,
                                                  uint32* __restrict__ Pout, int N, int nRows) {
    int chunk = blockIdx.x & 7;
    int k = (blockIdx.x >> 3) * 16 + (threadIdx.x >> 4);   // sorted position
    if (k >= N) return;
    uint4 m = meta[k];
    int beg = (int)m.x;
    int degp = (int)m.y;                                   // padded to multiple of 4
    float di = __uint_as_float(m.z);
    int node = (int)m.w;
    int w = (threadIdx.x >> 2) & 3;
    int c = threadIdx.x & 3;
    const float* tc = t_c + (size_t)chunk * nRows * 16 + c * 4;
    float4 a0 = make_float4(0.f, 0.f, 0.f, 0.f);
    float4 a1 = make_float4(0.f, 0.f, 0.f, 0.f);
    float4 a2 = make_float4(0.f, 0.f, 0.f, 0.f);
    float4 a3 = make_float4(0.f, 0.f, 0.f, 0.f);
    int end = beg + degp;
    for (int j = beg + 4 * w; j < end; j += 16) {
        ushort4 o = *(const ushort4*)(csr16 + j);          // 8B-aligned by construction
        float4 v0 = *(const float4*)(tc + ((size_t)o.x << 4));
        float4 v1 = *(const float4*)(tc + ((size_t)o.y << 4));
        float4 v2 = *(const float4*)(tc + ((size_t)o.z << 4));
        float4 v3 = *(const float4*)(tc + ((size_t)o.w << 4));
        a0.x += v0.x; a0.y += v0.y; a0.z += v0.z; a0.w += v0.w;
        a1.x += v1.x; a1.y += v1.y; a1.z += v1.z; a1.w += v1.w;
        a2.x += v2.x; a2.y += v2.y; a2.z += v2.z; a2.w += v2.w;
        a3.x += v3.x; a3.y += v3.y; a3.z += v3.z; a3.w += v3.w;
    }
    a0.x += a1.x; a0.y += a1.y; a0.z += a1.z; a0.w += a1.w;
    a2.x += a3.x; a2.y += a3.y; a2.z += a3.z; a2.w += a3.w;
    a0.x += a2.x; a0.y += a2.y; a0.z += a2.z; a0.w += a2.w;
    // combine 4 edge-ways (lane bits 2-3)
    a0.x += __shfl_xor(a0.x, 4); a0.y += __shfl_xor(a0.y, 4);
    a0.z += __shfl_xor(a0.z, 4); a0.w += __shfl_xor(a0.w, 4);
    a0.x += __shfl_xor(a0.x, 8); a0.y += __shfl_xor(a0.y, 8);
    a0.z += __shfl_xor(a0.z, 8); a0.w += __shfl_xor(a0.w, 8);
    if (w != 0) return;
    // t' pre-scaled by dinv: out = dinv[d]*(sum + t'[d]) + b
    float4 tv = *(const float4*)(tc + (size_t)node * 16);
    int col0 = chunk * 16 + c * 4;
    float4 b = *((const float4*)bias + (col0 >> 2));
    float4 r;
    r.x = fmaxf(fmaf(di, a0.x + tv.x, b.x), 0.f);
    r.y = fmaxf(fmaf(di, a0.y + tv.y, b.y), 0.f);
    r.z = fmaxf(fmaf(di, a0.z + tv.z, b.z), 0.f);
    r.w = fmaxf(fmaf(di, a0.w + tv.w, b.w), 0.f);
    uint4 p;
    p.x = split2p(r.x); p.y = split2p(r.y); p.z = split2p(r.z); p.w = split2p(r.w);
    *(uint4*)(Pout + (size_t)node * D + col0) = p;
}

extern "C" void kernel_launch(void* const* d_in, const int* in_sizes, int n_in,
                              void* d_out, int out_size, void* d_ws, size_t ws_size,
                              hipStream_t stream) {
    const float* x      = (const float*)d_in[0];
    const unsigned* edges = (const unsigned*)d_in[1];
    const float* W_pre  = (const float*)d_in[2];
    const float* b_pre  = (const float*)d_in[3];
    const float* W1     = (const float*)d_in[4];
    const float* b1     = (const float*)d_in[5];
    const float* W2     = (const float*)d_in[6];
    const float* b2     = (const float*)d_in[7];
    const float* W_post = (const float*)d_in[8];
    const float* b_post = (const float*)d_in[9];
    float* out = (float*)d_out;

    const int N = in_sizes[0] / D;        // 50000
    const int E = in_sizes[1] / 2;        // 800000
    const int nStrips = (N + 15) / 16;    // 3125
    const int Npad = nStrips * 16;
    const int nRows = Npad + 16;          // + sentinel rows (row Npad is the zero row)
    const int nBlk = (N + 255) / 256;     // 196
    const int csrCap = (E + 4 * N + 255) & ~255;   // padded csr capacity (shorts)

    // ---- workspace layout (persistent buffers) ----
    char* ws = (char*)d_ws;
    size_t off = 0;
    auto alloc = [&](size_t bytes) { void* p = ws + off; off += (bytes + 255) & ~(size_t)255; return p; };
    uint32* pairA = (uint32*)alloc((size_t)Npad * D * 4);   // pair plane A
    uint32* pairB = (uint32*)alloc((size_t)Npad * D * 4);   // pair plane B
    float*  bufT  = (float*)alloc((size_t)8 * nRows * 16 * 4);   // chunked pre-scaled t'[8][nRows][16]
    float*  dinv    = (float*)alloc((size_t)N * 4);
    int*    deg     = (int*)alloc((size_t)N * 4);
    int*    rowbeg  = (int*)alloc((size_t)N * 4);
    unsigned short* csr16 = (unsigned short*)alloc((size_t)csrCap * 2);
    uint4*  meta    = (uint4*)alloc((size_t)N * 16);
    uint32* wpre_p  = (uint32*)alloc(16384 * 4);
    uint32* w1_p    = (uint32*)alloc(16384 * 4);
    uint32* w2_p    = (uint32*)alloc(16384 * 4);
    uint32* wpost_p = (uint32*)alloc(6144 * 4);

    // ---- prep-phase temporaries OVERLAY bufT (first ~1 MB; sentinel rows are beyond 3 MB) ----
    {
        char* t = (char*)bufT;
        size_t toff = 0;
        auto talloc = [&](size_t bytes) { void* p = t + toff; toff += (bytes + 255) & ~(size_t)255; return p; };
        int* cursor     = (int*)talloc((size_t)N * 4);
        int* local_rank = (int*)talloc((size_t)N * 4);
        int* hist_blk   = (int*)talloc((size_t)nBlk * 256 * 4); // ~200 KB
        int* mode2      = (int*)talloc(256);                    // [0]=gmode, [1]=tail cursor
        int* binbase    = (int*)talloc(1024);
        int* ebase      = (int*)talloc(1024);
        int* gmode = mode2;
        int* tailcur = mode2 + 1;

        (void)hipMemsetAsync(mode2, 0, 8, stream);
        (void)hipMemsetAsync(deg, 0, (size_t)N * 4, stream);
        deg_raw<<<(E + 1023) / 1024, 256, 0, stream>>>(edges, deg, gmode, csr16, bufT, E, Npad, csrCap / 4, nRows,
                                                       W_pre, W1, W2, W_post, wpre_p, w1_p, w2_p, wpost_p);
        rank_block<<<nBlk, 256, 0, stream>>>(deg, dinv, local_rank, hist_blk, N);
        scan_blocks<<<1, 256, 0, stream>>>(hist_blk, binbase, ebase, nBlk);
        emit_perm<<<nBlk, 256, 0, stream>>>(deg, dinv, local_rank, hist_blk, binbase, ebase,
                                            tailcur, rowbeg, cursor, meta, N);
        fill_csr_raw<<<(E + 255) / 256, 256, 0, stream>>>(edges, gmode, rowbeg, cursor, csr16, E);
    }

    const int nGatherBlocks = ((N + 15) / 16) * 8;   // 3125 node-blocks x 8 XCD chunks
    const int gemmGrid = 391;   // 1564 slots x 2 strips each; 2 blocks/CU fit (67.5 KB LDS)

    // pre MLP: h1(pairB) = x @ W_pre + b_pre  (fp32 x split in-register)
    gemm_lds<1, 1><<<gemmGrid, 512, 0, stream>>>(x, wpre_p, b_pre, nullptr, nullptr, pairB, nStrips, N, nRows);

    // conv1: t' = dinv*(h1 @ W1) (chunked) ; h2(pairA) = relu(dinv*(gather+self) + b1)
    gemm_lds<0, 0><<<gemmGrid, 512, 0, stream>>>(pairB, w1_p, nullptr, dinv, bufT, nullptr, nStrips, N, nRows);
    gather_xcd<<<nGatherBlocks, 256, 0, stream>>>(csr16, meta, bufT, b1, pairA, N, nRows);

    // conv2
    gemm_lds<0, 0><<<gemmGrid, 512, 0, stream>>>(pairA, w2_p, nullptr, dinv, bufT, nullptr, nStrips, N, nRows);
    gather_xcd<<<nGatherBlocks, 256, 0, stream>>>(csr16, meta, bufT, b2, pairB, N, nRows);

    // post MLP: out = h3 @ W_post + b_post  (40 cols, padded to 48)
    gemm_post<<<256, 256, 0, stream>>>(pairB, wpost_p, b_post, out, nStrips, N, 40);
}